// Round 3
// baseline (320.211 us; speedup 1.0000x reference)
//
#include <hip/hip_runtime.h>
#include <stdint.h>

// GroupDRO loss: per-sample 3-class CE, group = mean(logits)<0.4 ? 0 : 1,
// subgroup = group*3 + label. Only 6 subgroup sums needed; everything else
// derives in the finalize kernel.
//
// R2 -> R3: perfectly-coalesced staging. Each block/iter stages 256 quads
// (12 KB logits + 4 KB labels) into LDS with global_load_lds width=16
// (lane-contiguous global src AND lds dst, per the wave-uniform-base rule),
// double-buffered: stage(it+1) issued before consuming it, so the async
// loads overlap the compute phase; the next iteration's __syncthreads
// (vmcnt drain) lands after ~a full compute phase.

constexpr int N_SAMPLES = 16777216;
constexpr int NQ = N_SAMPLES / 4;          // 4,194,304 quad-samples
constexpr int BLOCK = 256;
constexpr int GRID = 1024;                 // 4 blocks/CU, all co-resident
constexpr int STRIDE = GRID * BLOCK;       // quads per sweep
constexpr int ITERS = NQ / STRIDE;         // exactly 16, no tail
constexpr int WAVES = BLOCK / 64;

static_assert(ITERS * STRIDE == NQ, "exact tiling");

#define GLOBAL_AS __attribute__((address_space(1)))
#define LDS_AS    __attribute__((address_space(3)))

__device__ __forceinline__ void async_copy16(const void* g, void* l) {
    __builtin_amdgcn_global_load_lds((const GLOBAL_AS void*)g,
                                     (LDS_AS void*)l, 16, 0, 0);
}

__global__ __launch_bounds__(BLOCK) void dro_partial(
    const float* __restrict__ logits,
    const int*   __restrict__ labels,
    float*       __restrict__ partials)    // [GRID][6] in d_ws (overwritten)
{
    // Double-buffered staging: 2 x (768 float4 + 256 int4) = 32 KB.
    // NOTE: no padding — global_load_lds requires dst = wave-uniform base
    // + lane*16, i.e. dense lane-contiguous layout.
    __shared__ float4 slog[2][3 * BLOCK];
    __shared__ int4   slab[2][BLOCK];

    const float4* __restrict__ lgq = (const float4*)logits;  // NQ*3 float4
    const int4*   __restrict__ lbq = (const int4*)labels;    // NQ int4

    const int t = threadIdx.x;
    const int b = blockIdx.x;

    auto stage = [&](int it, int buf) {
        const int qbase  = it * STRIDE + b * BLOCK;  // first quad of this tile
        const int f4base = 3 * qbase;                // first float4 of this tile
        #pragma unroll
        for (int k = 0; k < 3; ++k)
            async_copy16(&lgq[f4base + k * BLOCK + t], &slog[buf][k * BLOCK + t]);
        async_copy16(&lbq[qbase + t], &slab[buf][t]);
    };

    float acc[6] = {0.f, 0.f, 0.f, 0.f, 0.f, 0.f};

    stage(0, 0);
    for (int it = 0; it < ITERS; ++it) {
        __syncthreads();   // drains stage(it)'s vmem; fences buffer reuse
        if (it + 1 < ITERS) stage(it + 1, (it + 1) & 1);  // fly over compute

        const int buf = it & 1;
        const float* xs = (const float*)&slog[buf][0];    // 3072 floats
        // thread t owns samples 4t..4t+3 of the tile: floats [12t, 12t+12)
        float4 v0 = *(const float4*)&xs[12 * t + 0];
        float4 v1 = *(const float4*)&xs[12 * t + 4];
        float4 v2 = *(const float4*)&xs[12 * t + 8];
        int4   l4 = slab[buf][t];

        float fs[12] = {v0.x, v0.y, v0.z, v0.w, v1.x, v1.y,
                        v1.z, v1.w, v2.x, v2.y, v2.z, v2.w};
        int   ls[4]  = {l4.x, l4.y, l4.z, l4.w};

        #pragma unroll
        for (int s = 0; s < 4; ++s) {
            float a = fs[3 * s], bb = fs[3 * s + 1], c = fs[3 * s + 2];
            int lab = ls[s];

            float m  = fmaxf(a, fmaxf(bb, c));
            float ea = __expf(a - m), eb = __expf(bb - m), ec = __expf(c - m);
            float lse = m + __logf(ea + eb + ec);
            float xl = (lab == 0) ? a : ((lab == 1) ? bb : c);
            float ce = lse - xl;

            float mean = (a + bb + c) * (1.0f / 3.0f);
            int g  = (mean < 0.4f) ? 0 : 1;
            int sg = g * 3 + lab;

            #pragma unroll
            for (int j = 0; j < 6; ++j)
                acc[j] += (j == sg) ? ce : 0.0f;   // branchless scatter
        }
    }

    // wave reduce (64 lanes)
    #pragma unroll
    for (int j = 0; j < 6; ++j) {
        #pragma unroll
        for (int off = 32; off > 0; off >>= 1)
            acc[j] += __shfl_down(acc[j], off, 64);
    }

    __shared__ float red[WAVES][6];
    const int wave = threadIdx.x >> 6;
    const int lane = threadIdx.x & 63;
    __syncthreads();   // staging buffers dead; reuse-safe ordering for red[]
    if (lane == 0) {
        #pragma unroll
        for (int j = 0; j < 6; ++j) red[wave][j] = acc[j];
    }
    __syncthreads();

    if (threadIdx.x < 6) {
        float s = 0.f;
        #pragma unroll
        for (int w = 0; w < WAVES; ++w) s += red[w][threadIdx.x];
        partials[blockIdx.x * 6 + threadIdx.x] = s;  // no atomics, no pre-zero
    }
}

__global__ __launch_bounds__(BLOCK) void dro_finalize(
    const float* __restrict__ partials,    // [GRID][6]
    const float* __restrict__ gw,
    float* __restrict__ out)
{
    float acc[6] = {0.f, 0.f, 0.f, 0.f, 0.f, 0.f};
    for (int b = threadIdx.x; b < GRID; b += BLOCK) {
        #pragma unroll
        for (int j = 0; j < 6; ++j) acc[j] += partials[b * 6 + j];
    }

    #pragma unroll
    for (int j = 0; j < 6; ++j) {
        #pragma unroll
        for (int off = 32; off > 0; off >>= 1)
            acc[j] += __shfl_down(acc[j], off, 64);
    }

    __shared__ float red[WAVES][6];
    const int wave = threadIdx.x >> 6;
    const int lane = threadIdx.x & 63;
    if (lane == 0) {
        #pragma unroll
        for (int j = 0; j < 6; ++j) red[wave][j] = acc[j];
    }
    __syncthreads();

    if (threadIdx.x == 0) {
        float sg[6];
        float tot = 0.f;
        #pragma unroll
        for (int j = 0; j < 6; ++j) {
            float s = 0.f;
            #pragma unroll
            for (int w = 0; w < WAVES; ++w) s += red[w][j];
            sg[j] = s;
            tot += s;
        }
        float g0 = sg[0] + sg[1] + sg[2];
        float g1 = sg[3] + sg[4] + sg[5];
        float total_loss = g0 * gw[0] + g1 * gw[1];
        float standard   = tot / (float)N_SAMPLES;
        float combined   = 0.7f * standard + 0.3f * total_loss;
        out[0] = combined;
        out[1] = g0;
        out[2] = g1;
        #pragma unroll
        for (int j = 0; j < 6; ++j) out[3 + j] = sg[j];
    }
}

extern "C" void kernel_launch(void* const* d_in, const int* in_sizes, int n_in,
                              void* d_out, int out_size, void* d_ws, size_t ws_size,
                              hipStream_t stream) {
    const float* logits = (const float*)d_in[0];
    const int*   labels = (const int*)d_in[1];
    const float* gw     = (const float*)d_in[2];
    float* partials = (float*)d_ws;    // GRID*6 floats, fully overwritten
    float* out      = (float*)d_out;   // [combined, g0, g1, sg0..sg5]

    dro_partial<<<GRID, BLOCK, 0, stream>>>(logits, labels, partials);
    dro_finalize<<<1, BLOCK, 0, stream>>>(partials, gw, out);
}